// Round 10
// baseline (351.631 us; speedup 1.0000x reference)
//
#include <hip/hip_runtime.h>
#include <math.h>

#define DD 1024
#define SS 4096
#define AP 128
#define LN_EPS 1e-6f
#define BK 32
#define BAND 384

typedef __bf16 bf16;
typedef __attribute__((ext_vector_type(4))) __bf16 bf16x4;
typedef __attribute__((ext_vector_type(8))) __bf16 bf16x8;
typedef __attribute__((ext_vector_type(4))) float f32x4;

#define GLOAD_LDS16(g, l)                                                   \
    __builtin_amdgcn_global_load_lds(                                        \
        (const __attribute__((address_space(1))) void*)(g),                  \
        (__attribute__((address_space(3))) void*)(l), 16, 0, 0)

// ---------------- merged prep: x cast | Wo cast | k1*g cast | 3 transposes | k1 row sums ----
__global__ __launch_bounds__(256) void prep_all(const float* __restrict__ x,
                                                const float* __restrict__ Wq,
                                                const float* __restrict__ Wk,
                                                const float* __restrict__ Wv,
                                                const float* __restrict__ Wo,
                                                const float* __restrict__ k1w,
                                                const float* __restrict__ k1b,
                                                const float* __restrict__ lng,
                                                const float* __restrict__ lnb,
                                                bf16* __restrict__ xb,
                                                bf16* __restrict__ Wob,
                                                bf16* __restrict__ k1g,
                                                bf16* __restrict__ Wtb,
                                                float* __restrict__ u1,
                                                float* __restrict__ c1b) {
    __shared__ float tile[64][65];
    const int bid = blockIdx.x;
    const int tid = threadIdx.x;
    if (bid < 16384) {  // x cast
        const int i = (bid * 256 + tid) * 4;
        const float4 a = *(const float4*)(x + i);
        bf16x4 o;
        o[0] = (__bf16)a.x; o[1] = (__bf16)a.y; o[2] = (__bf16)a.z; o[3] = (__bf16)a.w;
        *(bf16x4*)(xb + i) = o;
        return;
    }
    if (bid < 18432) {  // Wo cast / k1g = k1 * g cast
        const int b2 = bid - 16384;
        const int sel = b2 >> 10;
        const int bb = b2 & 1023;
        const float* s = sel ? k1w : Wo;
        bf16* d = sel ? k1g : Wob;
        const int i = (bb * 256 + tid) * 4;
        float4 a = *(const float4*)(s + i);
        if (sel) {
            const float4 g4 = *(const float4*)(lng + (i & (DD - 1)));
            a.x *= g4.x; a.y *= g4.y; a.z *= g4.z; a.w *= g4.w;
        }
        bf16x4 o;
        o[0] = (__bf16)a.x; o[1] = (__bf16)a.y; o[2] = (__bf16)a.z; o[3] = (__bf16)a.w;
        *(bf16x4*)(d + i) = o;
        return;
    }
    if (bid < 19200) {  // transpose-cast Wq/Wk/Wv
        const int t = bid - 18432;
        const int tz = t >> 8;
        const int tb_ = t & 255;
        const float* in = (tz == 0) ? Wq : (tz == 1) ? Wk : Wv;
        bf16* out = Wtb + ((size_t)tz << 20);
        const int r0 = (tb_ >> 4) * 64, c0 = (tb_ & 15) * 64;
        const int lr = tid >> 4;
        const int lc = (tid & 15) * 4;
#pragma unroll
        for (int rr = 0; rr < 4; rr++) {
            const int row = lr + rr * 16;
            const float4 v = *(const float4*)(in + (size_t)(r0 + row) * DD + c0 + lc);
            tile[row][lc] = v.x; tile[row][lc + 1] = v.y;
            tile[row][lc + 2] = v.z; tile[row][lc + 3] = v.w;
        }
        __syncthreads();
#pragma unroll
        for (int rr = 0; rr < 4; rr++) {
            const int row = lr + rr * 16;
            bf16x4 o;
            o[0] = (__bf16)tile[lc + 0][row];
            o[1] = (__bf16)tile[lc + 1][row];
            o[2] = (__bf16)tile[lc + 2][row];
            o[3] = (__bf16)tile[lc + 3][row];
            *(bf16x4*)(out + (size_t)(c0 + row) * DD + r0 + lc) = o;
        }
        return;
    }
    // prep_vec
    const int pv = bid - 19200;
    const int lane = tid & 63, wave = tid >> 6;
    const int n = pv * 4 + wave;
    const float* row = k1w + (size_t)n * DD + lane * 16;
    float su = 0.f, sb = 0.f;
#pragma unroll
    for (int q = 0; q < 4; q++) {
        const float4 a = *(const float4*)(row + q * 4);
        const float4 g4 = *(const float4*)(lng + lane * 16 + q * 4);
        const float4 b4 = *(const float4*)(lnb + lane * 16 + q * 4);
        su += a.x * g4.x + a.y * g4.y + a.z * g4.z + a.w * g4.w;
        sb += a.x * b4.x + a.y * b4.y + a.z * b4.z + a.w * b4.w;
    }
#pragma unroll
    for (int off = 32; off > 0; off >>= 1) {
        su += __shfl_xor(su, off);
        sb += __shfl_xor(sb, off);
    }
    if (lane == 0) {
        u1[n] = su;
        c1b[n] = sb + k1b[n];
    }
}

// ---------------- paired tiny 1024^3 GEMMs: z=0 -> Gt, z=1 -> W2 ----------------
__global__ __launch_bounds__(256) void gemm_pair(const bf16* __restrict__ A0,
                                                 const bf16* __restrict__ W0,
                                                 bf16* __restrict__ O0,
                                                 const bf16* __restrict__ A1,
                                                 const bf16* __restrict__ W1,
                                                 bf16* __restrict__ O1) {
    const bf16* A = blockIdx.z ? A1 : A0;
    const bf16* W = blockIdx.z ? W1 : W0;
    bf16* O = blockIdx.z ? O1 : O0;
    __shared__ bf16 As[128 * BK];
    __shared__ bf16 Bs[128 * BK];
    const int tid = threadIdx.x;
    const int lane = tid & 63;
    const int wave = tid >> 6;
    const int wm = wave & 1;
    const int wn = wave >> 1;
    const int m0 = blockIdx.y * 128;
    const int n0 = blockIdx.x * 128;

    const int c = wave * 64 + lane;
    const int ar = c >> 2;
    const int ac = (c & 3) << 3;
    char* AsB = (char*)As;
    char* BsB = (char*)Bs;
    const int lr = lane & 15;
    const int lk = (lane >> 4) << 3;

    f32x4 acc[4][4] = {};

    for (int kt = 0; kt < DD; kt += BK) {
        const bf16* ga0 = A + (size_t)(m0 + ar) * DD + kt + ac;
        const bf16* gb0 = W + (size_t)(n0 + ar) * DD + kt + ac;
        GLOAD_LDS16(ga0, AsB + wave * 1024);
        GLOAD_LDS16(ga0 + (size_t)64 * DD, AsB + 4096 + wave * 1024);
        GLOAD_LDS16(gb0, BsB + wave * 1024);
        GLOAD_LDS16(gb0 + (size_t)64 * DD, BsB + 4096 + wave * 1024);
        __syncthreads();

        bf16x8 af[4], bfr[4];
#pragma unroll
        for (int i = 0; i < 4; i++)
            af[i] = *(const bf16x8*)&As[(wm * 64 + i * 16 + lr) * BK + lk];
#pragma unroll
        for (int j = 0; j < 4; j++)
            bfr[j] = *(const bf16x8*)&Bs[(wn * 64 + j * 16 + lr) * BK + lk];
#pragma unroll
        for (int i = 0; i < 4; i++)
#pragma unroll
            for (int j = 0; j < 4; j++)
                acc[i][j] = __builtin_amdgcn_mfma_f32_16x16x32_bf16(af[i], bfr[j], acc[i][j], 0, 0, 0);
        __syncthreads();
    }

#pragma unroll
    for (int i = 0; i < 4; i++) {
        const int row = m0 + wm * 64 + i * 16 + ((lane >> 4) << 2);
#pragma unroll
        for (int j = 0; j < 4; j++) {
            const int col = n0 + wn * 64 + j * 16 + (lane & 15);
#pragma unroll
            for (int rr = 0; rr < 4; rr++)
                O[(size_t)(row + rr) * DD + col] = (__bf16)acc[i][j][rr];
        }
    }
}

// ---------------- merged U / Vt2 GEMM: 256x128 tiles, 512 threads, flat grid 1024 ----------------
__global__ __launch_bounds__(512) void gemm_uv(const bf16* __restrict__ xb,
                                               const bf16* __restrict__ Gt,
                                               const bf16* __restrict__ W2,
                                               bf16* __restrict__ Ub,
                                               bf16* __restrict__ Vt2) {
    __shared__ bf16 As[256 * BK];
    __shared__ bf16 Bs[128 * BK];
    int id = blockIdx.x;
    const bf16* A;
    const bf16* W;
    bf16* O;
    int m0, n0, ldo;
    if (id < 512) {
        A = xb; W = Gt; O = Ub;
        m0 = (id & 63) * 256; n0 = (id >> 6) * 128; ldo = DD;
    } else {
        id -= 512;
        A = W2; W = xb; O = Vt2;
        m0 = (id >> 7) * 256; n0 = (id & 127) * 128; ldo = 4 * SS;
    }
    const int tid = threadIdx.x;
    const int lane = tid & 63;
    const int wave = tid >> 6;
    const int wm = wave & 3;
    const int wn = wave >> 2;

    const int ar = tid >> 2;
    const int ac = (tid & 3) << 3;
    char* AsB = (char*)As;
    char* BsB = (char*)Bs;
    const int lr = lane & 15;
    const int lk = (lane >> 4) << 3;

    f32x4 acc[4][4] = {};

    for (int kt = 0; kt < DD; kt += BK) {
        const bf16* ga0 = A + (size_t)(m0 + ar) * DD + kt + ac;
        const bf16* gb0 = W + (size_t)(n0 + ar) * DD + kt + ac;
        GLOAD_LDS16(ga0, AsB + wave * 1024);
        GLOAD_LDS16(ga0 + (size_t)128 * DD, AsB + 8192 + wave * 1024);
        GLOAD_LDS16(gb0, BsB + wave * 1024);
        __syncthreads();

        bf16x8 af[4], bfr[4];
#pragma unroll
        for (int i = 0; i < 4; i++)
            af[i] = *(const bf16x8*)&As[(wm * 64 + i * 16 + lr) * BK + lk];
#pragma unroll
        for (int j = 0; j < 4; j++)
            bfr[j] = *(const bf16x8*)&Bs[(wn * 64 + j * 16 + lr) * BK + lk];
#pragma unroll
        for (int i = 0; i < 4; i++)
#pragma unroll
            for (int j = 0; j < 4; j++)
                acc[i][j] = __builtin_amdgcn_mfma_f32_16x16x32_bf16(af[i], bfr[j], acc[i][j], 0, 0, 0);
        __syncthreads();
    }

#pragma unroll
    for (int i = 0; i < 4; i++) {
        const int row = m0 + wm * 64 + i * 16 + ((lane >> 4) << 2);
#pragma unroll
        for (int j = 0; j < 4; j++) {
            const int col = n0 + wn * 64 + j * 16 + (lane & 15);
#pragma unroll
            for (int rr = 0; rr < 4; rr++)
                O[(size_t)(row + rr) * ldo + col] = (__bf16)acc[i][j][rr];
        }
    }
}

// ---------------- k1 GEMM, folded LN1 + in-block row stats, partial-only output ------
__global__ __launch_bounds__(512) void gemm_k1(const bf16* __restrict__ T,
                                               const bf16* __restrict__ k1g,
                                               const float* __restrict__ part_t,
                                               const float* __restrict__ u1,
                                               const float* __restrict__ c1b,
                                               const float* __restrict__ lng,
                                               const float* __restrict__ k2w,
                                               float* __restrict__ part_h) {
    __shared__ bf16 As[256 * BK];
    __shared__ bf16 Bs[128 * BK];
    __shared__ float lmu[256], lrs[256];
    const int m0 = blockIdx.x * 256;
    const int n0 = blockIdx.y * 128;
    const int tid = threadIdx.x;
    const int lane = tid & 63;
    const int wave = tid >> 6;
    const int wm = wave & 3;
    const int wn = wave >> 2;

    const int ar = tid >> 2;
    const int ac = (tid & 3) << 3;
    char* AsB = (char*)As;
    char* BsB = (char*)Bs;
    const int lr = lane & 15;
    const int lk = (lane >> 4) << 3;

    if (tid < 256) {
        const float* p = part_t + (size_t)(m0 + tid) * 32;
        float s1 = 0.f, s2 = 0.f;
#pragma unroll
        for (int s = 0; s < 8; s++) {
            const float4 v = *(const float4*)(p + s * 4);
            s1 += v.x + v.z;
            s2 += v.y + v.w;
        }
        const float m = s1 * (1.f / DD);
        lmu[tid] = m;
        lrs[tid] = rsqrtf(s2 * (1.f / DD) - m * m + LN_EPS);
    }

    f32x4 acc[4][4] = {};

    for (int kt = 0; kt < DD; kt += BK) {
        const bf16* ga0 = T + (size_t)(m0 + ar) * DD + kt + ac;
        const bf16* gb0 = k1g + (size_t)(n0 + ar) * DD + kt + ac;
        GLOAD_LDS16(ga0, AsB + wave * 1024);
        GLOAD_LDS16(ga0 + (size_t)128 * DD, AsB + 8192 + wave * 1024);
        GLOAD_LDS16(gb0, BsB + wave * 1024);
        __syncthreads();

        bf16x8 af[4], bfr[4];
#pragma unroll
        for (int i = 0; i < 4; i++)
            af[i] = *(const bf16x8*)&As[(wm * 64 + i * 16 + lr) * BK + lk];
#pragma unroll
        for (int j = 0; j < 4; j++)
            bfr[j] = *(const bf16x8*)&Bs[(wn * 64 + j * 16 + lr) * BK + lk];
#pragma unroll
        for (int i = 0; i < 4; i++)
#pragma unroll
            for (int j = 0; j < 4; j++)
                acc[i][j] = __builtin_amdgcn_mfma_f32_16x16x32_bf16(af[i], bfr[j], acc[i][j], 0, 0, 0);
        __syncthreads();
    }

    float u1v[4], cbv[4], ugv[4];
#pragma unroll
    for (int j = 0; j < 4; j++) {
        const int col = n0 + wn * 64 + j * 16 + (lane & 15);
        u1v[j] = u1[col];
        cbv[j] = c1b[col];
        ugv[j] = lng[col] * k2w[col];
    }
    const int strip = blockIdx.y * 2 + wn;
#pragma unroll
    for (int i = 0; i < 4; i++) {
#pragma unroll
        for (int rr = 0; rr < 4; rr++) {
            const int lrow = wm * 64 + i * 16 + ((lane >> 4) << 2) + rr;
            const int row = m0 + lrow;
            const float mr = lmu[lrow], rs = lrs[lrow];
            float s1 = 0.f, s2 = 0.f, s3 = 0.f;
#pragma unroll
            for (int j = 0; j < 4; j++) {
                const float v = rs * (acc[i][j][rr] - mr * u1v[j]) + cbv[j];
                const float h = fmaxf(v, 0.f);
                s1 += h; s2 += h * h; s3 += h * ugv[j];
            }
#pragma unroll
            for (int off = 8; off > 0; off >>= 1) {
                s1 += __shfl_xor(s1, off);
                s2 += __shfl_xor(s2, off);
                s3 += __shfl_xor(s3, off);
            }
            if ((lane & 15) == 0) {
                float* p = part_h + (size_t)row * 48 + strip * 3;
                p[0] = s1; p[1] = s2; p[2] = s3;
            }
        }
    }
}

// ---------------- fused banded scores + masked softmax: P = softmax(mask(U @ x_band^T)) ---
// grid 256 (64-row tiles), 512 threads = 8 waves; wave w owns 64 rows x 48 cols.
__global__ __launch_bounds__(512) void attn_ss(const bf16* __restrict__ U,
                                               const bf16* __restrict__ X,
                                               bf16* __restrict__ P) {
    __shared__ bf16 As[64 * BK];    // 4 KB
    __shared__ bf16 Bs[BAND * BK];  // 24 KB
    __shared__ float red8[64][8];
    __shared__ float rowv[64];
    const int tid = threadIdx.x;
    const int lane = tid & 63;
    const int wave = tid >> 6;  // 0..7
    const int m0 = blockIdx.x * 64;
    const int i0seq = m0 & (SS - 1);
    const int jstart = ((i0seq >> 7) << 7) - 128;    // seq-local band base
    const long w0 = (long)(m0 - i0seq) + jstart;     // global X row base (OOB -> guards, masked)

    const int lr = lane & 15;
    const int lk = (lane >> 4) << 3;
    const int quad = lane >> 4;
    char* AsB = (char*)As;
    char* BsB = (char*)Bs;
    const float scale = 0.03125f;  // 1/sqrt(1024)

    f32x4 acc[4][3] = {};

    for (int kt = 0; kt < DD; kt += BK) {
#pragma unroll
        for (int q = 0; q < 3; q++) {
            const int c = (wave * 3 + q) * 64 + lane;  // 1536 B-chunks
            const int br = c >> 2;
            const int bc = (c & 3) << 3;
            GLOAD_LDS16(X + (w0 + br) * DD + kt + bc, BsB + (wave * 3 + q) * 1024);
        }
        if (wave < 4) {
            const int c = wave * 64 + lane;  // 256 A-chunks
            const int ar = c >> 2;
            const int ac2 = (c & 3) << 3;
            GLOAD_LDS16(U + (size_t)(m0 + ar) * DD + kt + ac2, AsB + wave * 1024);
        }
        __syncthreads();

        bf16x8 af[4], bfr[3];
#pragma unroll
        for (int i = 0; i < 4; i++)
            af[i] = *(const bf16x8*)&As[(i * 16 + lr) * BK + lk];
#pragma unroll
        for (int j = 0; j < 3; j++)
            bfr[j] = *(const bf16x8*)&Bs[(wave * 48 + j * 16 + lr) * BK + lk];
#pragma unroll
        for (int i = 0; i < 4; i++)
#pragma unroll
            for (int j = 0; j < 3; j++)
                acc[i][j] = __builtin_amdgcn_mfma_f32_16x16x32_bf16(af[i], bfr[j], acc[i][j], 0, 0, 0);
        __syncthreads();
    }

    // mask + scale, per-row partial max over this wave's 48 cols
    float pm[4][4];
#pragma unroll
    for (int i = 0; i < 4; i++) {
#pragma unroll
        for (int rg = 0; rg < 4; rg++) {
            const int rl = i * 16 + quad * 4 + rg;
            const int iseq = (m0 + rl) & (SS - 1);
            float mx = -INFINITY;
#pragma unroll
            for (int j = 0; j < 3; j++) {
                const int jseq = jstart + wave * 48 + j * 16 + lr;
                const int dj = jseq - iseq;
                const bool valid = (jseq >= 0) && (jseq < SS) && (dj != 0) && (dj <= AP) && (dj >= -AP);
                const float e = valid ? acc[i][j][rg] * scale : -INFINITY;
                acc[i][j][rg] = e;
                mx = fmaxf(mx, e);
            }
            pm[i][rg] = mx;
        }
    }
#pragma unroll
    for (int off = 1; off < 16; off <<= 1)
#pragma unroll
        for (int i = 0; i < 4; i++)
#pragma unroll
            for (int rg = 0; rg < 4; rg++)
                pm[i][rg] = fmaxf(pm[i][rg], __shfl_xor(pm[i][rg], off));
    if (lr == 0)
#pragma unroll
        for (int i = 0; i < 4; i++)
#pragma unroll
            for (int rg = 0; rg < 4; rg++)
                red8[i * 16 + quad * 4 + rg][wave] = pm[i][rg];
    __syncthreads();
    if (tid < 64) {
        float mx = -INFINITY;
#pragma unroll
        for (int w = 0; w < 8; w++) mx = fmaxf(mx, red8[tid][w]);
        rowv[tid] = mx;
    }
    __syncthreads();

    // exp + per-row partial sum
    float ps[4][4];
#pragma unroll
    for (int i = 0; i < 4; i++) {
#pragma unroll
        for (int rg = 0; rg < 4; rg++) {
            const float mr = rowv[i * 16 + quad * 4 + rg];
            float s = 0.f;
#pragma unroll
            for (int j = 0; j < 3; j++) {
                const float p = __expf(acc[i][j][rg] - mr);
                acc[i][j][rg] = p;
                s += p;
            }
            ps[i][rg] = s;
        }
    }
#pragma unroll
    for (int off = 1; off < 16; off <<= 1)
#pragma unroll
        for (int i = 0; i < 4; i++)
#pragma unroll
            for (int rg = 0; rg < 4; rg++)
                ps[i][rg] += __shfl_xor(ps[i][rg], off);
    if (lr == 0)
#pragma unroll
        for (int i = 0; i < 4; i++)
#pragma unroll
            for (int rg = 0; rg < 4; rg++)
                red8[i * 16 + quad * 4 + rg][wave] = ps[i][rg];
    __syncthreads();
    if (tid < 64) {
        float s = 0.f;
#pragma unroll
        for (int w = 0; w < 8; w++) s += red8[tid][w];
        rowv[tid] = 1.f / s;
    }
    __syncthreads();

#pragma unroll
    for (int i = 0; i < 4; i++) {
#pragma unroll
        for (int rg = 0; rg < 4; rg++) {
            const int rl = i * 16 + quad * 4 + rg;
            const float inv = rowv[rl];
            const size_t base = (size_t)(m0 + rl) * BAND + wave * 48 + lr;
#pragma unroll
            for (int j = 0; j < 3; j++)
                P[base + j * 16] = (__bf16)(acc[i][j][rg] * inv);
        }
    }
}

// ---------------- attention pass B + residual + T row-partials ----------------
// 128x256 tiles, 512 threads, grid (x = 128 t, y = 4 n-blocks of 256)
__global__ __launch_bounds__(512) void attn_pv_mfma(const bf16* __restrict__ P,
                                                    const bf16* __restrict__ Vt,
                                                    const bf16* __restrict__ xres,
                                                    bf16* __restrict__ T,
                                                    float* __restrict__ part_t) {
    __shared__ bf16 As[128 * BK];   // P tile   8KB
    __shared__ bf16 Bs[256 * BK];   // Vt tile 16KB
    const int tid = threadIdx.x;
    const int lane = tid & 63;
    const int wave = tid >> 6;
    const int wm = wave & 1;
    const int wn = wave >> 1;
    const int t = blockIdx.x;
    const int m0 = t * 128;
    const int n0 = blockIdx.y * 256;
    const bf16* Wb = Vt + (long)t * 128 - 128;

    const int ar = tid >> 2;
    const int ac = (tid & 3) << 3;
    char* AsB = (char*)As;
    char* BsB = (char*)Bs;
    const int lr = lane & 15;
    const int lk = (lane >> 4) << 3;

    f32x4 acc[4][4] = {};

    for (int kt = 0; kt < BAND; kt += BK) {
        const bf16* ga0 = P + (size_t)(m0 + ar) * BAND + kt + ac;
        const bf16* gb0 = Wb + (size_t)(n0 + ar) * (4 * SS) + kt + ac;
        GLOAD_LDS16(ga0, AsB + wave * 1024);
        GLOAD_LDS16(gb0, BsB + wave * 1024);
        GLOAD_LDS16(gb0 + (size_t)128 * (4 * SS), BsB + 8192 + wave * 1024);
        __syncthreads();

        bf16x8 af[4], bfr[4];
#pragma unroll
        for (int i = 0; i < 4; i++)
            af[i] = *(const bf16x8*)&As[(wm * 64 + i * 16 + lr) * BK + lk];
#pragma unroll
        for (int j = 0; j < 4; j++)
            bfr[j] = *(const bf16x8*)&Bs[(wn * 64 + j * 16 + lr) * BK + lk];
#pragma unroll
        for (int i = 0; i < 4; i++)
#pragma unroll
            for (int j = 0; j < 4; j++)
                acc[i][j] = __builtin_amdgcn_mfma_f32_16x16x32_bf16(af[i], bfr[j], acc[i][j], 0, 0, 0);
        __syncthreads();
    }

    const int strip = blockIdx.y * 4 + wn;
#pragma unroll
    for (int i = 0; i < 4; i++) {
#pragma unroll
        for (int rr = 0; rr < 4; rr++) {
            const int row = m0 + wm * 64 + i * 16 + ((lane >> 4) << 2) + rr;
            float s1 = 0.f, s2 = 0.f;
#pragma unroll
            for (int j = 0; j < 4; j++) {
                const int col = n0 + wn * 64 + j * 16 + (lane & 15);
                const size_t idx = (size_t)row * DD + col;
                const __bf16 tv_b = (__bf16)(acc[i][j][rr] + (float)xres[idx]);
                T[idx] = tv_b;
                const float tv = (float)tv_b;
                s1 += tv; s2 += tv * tv;
            }
#pragma unroll
            for (int off = 8; off > 0; off >>= 1) {
                s1 += __shfl_xor(s1, off);
                s2 += __shfl_xor(s2, off);
            }
            if ((lane & 15) == 0) {
                float2 st; st.x = s1; st.y = s2;
                *(float2*)(part_t + (size_t)row * 32 + strip * 2) = st;
            }
        }
    }
}

// ---------------- reduce H partials -> sigmoid head ----------------
__global__ __launch_bounds__(256) void ln_k2_p(const float* __restrict__ part_h,
                                               const float* __restrict__ g,
                                               const float* __restrict__ bta,
                                               const float* __restrict__ w2,
                                               const float* __restrict__ b2,
                                               float* __restrict__ out) {
    __shared__ float red[256], red2[256];
    const int tid = threadIdx.x;
    const float4 g4 = *(const float4*)(g + tid * 4);
    const float4 w4 = *(const float4*)(w2 + tid * 4);
    const float4 b4 = *(const float4*)(bta + tid * 4);
    red[tid] = g4.x * w4.x + g4.y * w4.y + g4.z * w4.z + g4.w * w4.w;
    red2[tid] = b4.x * w4.x + b4.y * w4.y + b4.z * w4.z + b4.w * w4.w;
    __syncthreads();
    for (int s = 128; s > 0; s >>= 1) {
        if (tid < s) { red[tid] += red[tid + s]; red2[tid] += red2[tid + s]; }
        __syncthreads();
    }
    const float sum_u = red[0];
    const float sum_bw = red2[0];

    const int r = blockIdx.x * 256 + tid;
    const float* p = part_h + (size_t)r * 48;
    float s1 = 0.f, s2 = 0.f, s3 = 0.f;
#pragma unroll
    for (int s = 0; s < 16; s++) {
        s1 += p[s * 3 + 0];
        s2 += p[s * 3 + 1];
        s3 += p[s * 3 + 2];
    }
    const float m = s1 * (1.f / DD);
    const float var = s2 * (1.f / DD) - m * m;
    const float rs = rsqrtf(var + LN_EPS);
    const float z = rs * (s3 - m * sum_u) + sum_bw + b2[0];
    out[r] = 1.f / (1.f + __expf(-z));
}

extern "C" void kernel_launch(void* const* d_in, const int* in_sizes, int n_in,
                              void* d_out, int out_size, void* d_ws, size_t ws_size,
                              hipStream_t stream) {
    const float* x   = (const float*)d_in[0];
    const float* Wq  = (const float*)d_in[1];
    const float* Wk  = (const float*)d_in[2];
    const float* Wv  = (const float*)d_in[3];
    const float* Wo  = (const float*)d_in[4];
    const float* k1w = (const float*)d_in[5];
    const float* k1b = (const float*)d_in[6];
    const float* k2w = (const float*)d_in[7];
    const float* k2b = (const float*)d_in[8];
    const float* lng = (const float*)d_in[9];
    const float* lnb = (const float*)d_in[10];
    float* out = (float*)d_out;

    const int N = 4 * SS;  // 16384 rows
    char* ws = (char*)d_ws;
    // layout (MB). Banded passes read +/-256KB around xb and Vt2 -> neighbors
    // must be valid bf16 (Ub | xb | Vt2 | P). Masked / zero-weighted.
    bf16*  Ub   = (bf16*)(ws);                          //   0..32
    bf16*  xb   = (bf16*)(ws + ((size_t)32  << 20));    //  32..64
    bf16*  Vt2  = (bf16*)(ws + ((size_t)64  << 20));    //  64..96  [1024][16384]
    bf16*  P    = (bf16*)(ws + ((size_t)96  << 20));    //  96..108
    bf16*  T    = (bf16*)(ws + ((size_t)164 << 20));    // 164..196
    bf16*  Wtb  = (bf16*)(ws + ((size_t)196 << 20));    // 196..202: Wq^T, Wk^T, Wv^T
    bf16*  Wqtb = Wtb;
    bf16*  Wktb = Wqtb + (1 << 20);
    bf16*  Wvtb = Wktb + (1 << 20);
    bf16*  Wob  = Wvtb + (1 << 20);                     // 202..204
    bf16*  k1g  = Wob  + (1 << 20);                     // 204..206
    bf16*  Gtb  = k1g  + (1 << 20);                     // 206..208
    bf16*  W2b  = Gtb  + (1 << 20);                     // 208..210
    float* u1     = (float*)(ws + ((size_t)210 << 20)); // 4 KB
    float* c1b    = u1 + DD;                            // 4 KB
    float* part_t = (float*)(ws + ((size_t)211 << 20)); // 211..213: [16384][16][2]
    float* part_h = (float*)(ws + ((size_t)214 << 20)); // 214..217: [16384][16][3]

    dim3 tb(256);

    prep_all<<<19456, tb, 0, stream>>>(x, Wq, Wk, Wv, Wo, k1w, k1b, lng, lnb,
                                       xb, Wob, k1g, Wtb, u1, c1b);

    // Gt = Wk^T @ Wq (bt-layout)  |  W2 = Wo @ Wv (bt on Wv^T)
    gemm_pair<<<dim3(8, 8, 2), tb, 0, stream>>>(Wktb, Wqtb, Gtb, Wob, Wvtb, W2b);

    gemm_uv<<<1024, dim3(512), 0, stream>>>(xb, Gtb, W2b, Ub, Vt2);

    attn_ss<<<256, dim3(512), 0, stream>>>(Ub, xb, P);
    attn_pv_mfma<<<dim3(N / 128, 4), dim3(512), 0, stream>>>(P, Vt2, xb, T, part_t);

    gemm_k1<<<dim3(64, 8), dim3(512), 0, stream>>>(T, k1g, part_t, u1, c1b, lng, k2w, part_h);
    ln_k2_p<<<N / 256, tb, 0, stream>>>(part_h, lng, lnb, k2w, k2b, out);
}